// Round 17
// baseline (693.566 us; speedup 1.0000x reference)
//
#include <hip/hip_runtime.h>
#include <hip/hip_bf16.h>
#include <cmath>

#define BATCH 8
#define CIN 64
#define COUT 128
#define NPTS 16384
#define RES 32
#define R3 32768
#define NGROUP 8
#define GSIZE 16

typedef __hip_bfloat16 bf16;
typedef __attribute__((ext_vector_type(8))) short short8;
typedef __attribute__((ext_vector_type(4))) float f32x4;

__device__ inline float b2f(ushort u) { union { float f; uint v; } x; x.v = ((uint)u) << 16; return x.f; }
__device__ inline ushort f2bu(float f) { __hip_bfloat16 h = __float2bfloat16(f); return *reinterpret_cast<ushort*>(&h); }

// ---------------- coord stats ----------------
__global__ __launch_bounds__(256) void coord_stats_k(const float* __restrict__ coords,
                                                     float* __restrict__ bstats) {
    int b = blockIdx.x;
    int t = threadIdx.x;
    __shared__ float red[256];
    __shared__ float means[3];
    for (int c = 0; c < 3; ++c) {
        float acc = 0.f;
        const float* p = coords + ((size_t)b * 3 + c) * NPTS;
        for (int n = t; n < NPTS; n += 256) acc += p[n];
        red[t] = acc; __syncthreads();
        for (int s = 128; s > 0; s >>= 1) { if (t < s) red[t] += red[t + s]; __syncthreads(); }
        if (t == 0) means[c] = red[0] * (1.f / NPTS);
        __syncthreads();
    }
    float m0 = means[0], m1 = means[1], m2 = means[2];
    const float* px = coords + ((size_t)b * 3 + 0) * NPTS;
    const float* py = coords + ((size_t)b * 3 + 1) * NPTS;
    const float* pz = coords + ((size_t)b * 3 + 2) * NPTS;
    float mx = 0.f;
    for (int n = t; n < NPTS; n += 256) {
        float dx = px[n] - m0, dy = py[n] - m1, dz = pz[n] - m2;
        mx = fmaxf(mx, sqrtf(dx * dx + dy * dy + dz * dz));
    }
    red[t] = mx; __syncthreads();
    for (int s = 128; s > 0; s >>= 1) { if (t < s) red[t] = fmaxf(red[t], red[t + s]); __syncthreads(); }
    if (t == 0) {
        bstats[b * 4 + 0] = m0; bstats[b * 4 + 1] = m1; bstats[b * 4 + 2] = m2;
        bstats[b * 4 + 3] = 1.f / (2.f * red[0]);
    }
}

// ---------------- per-point voxel index + nc4 + count ----------------
__global__ __launch_bounds__(256) void vox_idx_k(const float* __restrict__ coords,
                                                 const float* __restrict__ bstats,
                                                 float4* __restrict__ nc4,
                                                 int* __restrict__ vidx,
                                                 int* __restrict__ slot,
                                                 unsigned int* __restrict__ cnts) {
    int g = blockIdx.x * 256 + threadIdx.x;
    int b = g >> 14, n = g & (NPTS - 1);
    float m0 = bstats[b * 4 + 0], m1 = bstats[b * 4 + 1], m2 = bstats[b * 4 + 2];
    float sc = bstats[b * 4 + 3];
    float x = coords[((size_t)b * 3 + 0) * NPTS + n];
    float y = coords[((size_t)b * 3 + 1) * NPTS + n];
    float z = coords[((size_t)b * 3 + 2) * NPTS + n];
    float ncx = fminf(fmaxf(((x - m0) * sc + 0.5f) * (float)RES, 0.f), RES - 1.f);
    float ncy = fminf(fmaxf(((y - m1) * sc + 0.5f) * (float)RES, 0.f), RES - 1.f);
    float ncz = fminf(fmaxf(((z - m2) * sc + 0.5f) * (float)RES, 0.f), RES - 1.f);
    nc4[g] = make_float4(ncx, ncy, ncz, 0.f);
    int ix = min(max((int)rintf(ncx), 0), RES - 1);  // rintf = half-even = jnp.round
    int iy = min(max((int)rintf(ncy), 0), RES - 1);
    int iz = min(max((int)rintf(ncz), 0), RES - 1);
    int v = b * R3 + (ix * RES + iy) * RES + iz;
    vidx[g] = v;
    slot[g] = (int)atomicAdd(&cnts[v], 1u);
}

// ---------------- feature transpose: [b][64][N] fp32 -> [g][64] bf16 ----------------
__global__ __launch_bounds__(256) void transpose_feats_k(const float* __restrict__ feats,
                                                         bf16* __restrict__ featTb) {
    int blk = blockIdx.x;
    int b = blk >> 8, ntile = blk & 255;
    int t = threadIdx.x;
    __shared__ float lds[64][65];
    for (int e = t; e < 64 * 64; e += 256) {
        int c = e >> 6, n = e & 63;
        lds[c][n] = feats[((size_t)b * CIN + c) * NPTS + ntile * 64 + n];
    }
    __syncthreads();
    for (int e = t; e < 64 * 8; e += 256) {   // 512: (n, ci-octet)
        int n = e >> 3, oct = e & 7;
        ushort o[8];
#pragma unroll
        for (int j = 0; j < 8; ++j) o[j] = f2bu(lds[oct * 8 + j][n]);
        *(short8*)(featTb + ((((size_t)b << 14) + ntile * 64 + n) * CIN) + oct * 8) = *(short8*)o;
    }
}

// ---------------- scan ----------------
__global__ __launch_bounds__(256) void scan1_k(const unsigned int* __restrict__ cnts,
                                               unsigned int* __restrict__ offs,
                                               unsigned int* __restrict__ part) {
    int t = threadIdx.x;
    int g = blockIdx.x * 256 + t;
    unsigned int v = cnts[g];
    __shared__ unsigned int s[256];
    s[t] = v; __syncthreads();
    for (int d = 1; d < 256; d <<= 1) {
        unsigned int x = (t >= d) ? s[t - d] : 0u;
        __syncthreads();
        s[t] += x;
        __syncthreads();
    }
    offs[g] = s[t] - v;
    if (t == 255) part[blockIdx.x] = s[255];
}

__global__ __launch_bounds__(1024) void scan2_k(unsigned int* __restrict__ part) {
    int t = threadIdx.x;
    unsigned int v = part[t];
    __shared__ unsigned int s[1024];
    s[t] = v; __syncthreads();
    for (int d = 1; d < 1024; d <<= 1) {
        unsigned int x = (t >= d) ? s[t - d] : 0u;
        __syncthreads();
        s[t] += x;
        __syncthreads();
    }
    part[t] = s[t] - v;
}

__global__ __launch_bounds__(256) void scan3_k(unsigned int* __restrict__ offs,
                                               const unsigned int* __restrict__ part) {
    int g = blockIdx.x * 256 + threadIdx.x;
    offs[g] += part[blockIdx.x];
}

// ---------------- scatter global point id into CSR ----------------
__global__ __launch_bounds__(256) void scatter_pts_k(const int* __restrict__ vidx,
                                                     const int* __restrict__ slot,
                                                     const unsigned int* __restrict__ offs,
                                                     unsigned int* __restrict__ pidx2) {
    int g = blockIdx.x * 256 + threadIdx.x;
    int v = vidx[g];
    pidx2[offs[v] + slot[g]] = (unsigned int)g;
}

// ---------------- gather: CSR mean -> bf16 channel-last vox ----------------
__global__ __launch_bounds__(256) void gather_k(const bf16* __restrict__ featTb,
                                                const unsigned int* __restrict__ cnts,
                                                const unsigned int* __restrict__ offs,
                                                const unsigned int* __restrict__ pidx2,
                                                bf16* __restrict__ voxCL) {
    int u = blockIdx.x * 256 + threadIdx.x;
    int v = u >> 3;
    int l8 = u & 7;
    unsigned int cnt = cnts[v];
    unsigned int off = offs[v];
    float acc[8] = {0.f, 0.f, 0.f, 0.f, 0.f, 0.f, 0.f, 0.f};
    for (unsigned int i = 0; i < cnt; ++i) {
        unsigned int g = pidx2[off + i];
        short8 f = *(const short8*)(featTb + (size_t)g * CIN + l8 * 8);
#pragma unroll
        for (int j = 0; j < 8; ++j) acc[j] += b2f((ushort)f[j]);
    }
    float inv = 1.f / fmaxf((float)cnt, 1.f);
    ushort o[8];
#pragma unroll
    for (int j = 0; j < 8; ++j) o[j] = f2bu(acc[j] * inv);
    *(short8*)(voxCL + (size_t)v * CIN + l8 * 8) = *(short8*)o;
}

// ---------------- weight reorder: [co][ci][27] fp32 -> [t][c32][co][kb][8] bf16 ----------------
template <int CIN_T>
__global__ __launch_bounds__(256) void wreorder_k(const float* __restrict__ w,
                                                  bf16* __restrict__ wf) {
    const int NC = CIN_T / 32;
    int u = blockIdx.x * 256 + threadIdx.x;
    if (u >= 27 * NC * 128 * 4) return;
    int kb = u & 3;
    int co = (u >> 2) & 127;
    int c32 = (u >> 9) % NC;
    int t = u / (512 * NC);
    int cibase = c32 * 32 + kb * 8;
    ushort o[8];
#pragma unroll
    for (int j = 0; j < 8; ++j)
        o[j] = f2bu(w[((size_t)co * CIN_T + cibase + j) * 27 + t]);
    *(short8*)(wf + (size_t)u * 8) = *(short8*)o;
}

// ---------------- wp reorder: [co][64] fp32 -> [c32][co][kb][8] bf16 (MFMA A-frag order) ----------------
__global__ __launch_bounds__(256) void wpreorder_k(const float* __restrict__ wp,
                                                   bf16* __restrict__ wpb) {
    int u = blockIdx.x * 256 + threadIdx.x;  // 2*128*4 = 1024
    if (u >= 1024) return;
    int kb = u & 3;
    int co = (u >> 2) & 127;
    int c32 = u >> 9;
    ushort o[8];
#pragma unroll
    for (int j = 0; j < 8; ++j)
        o[j] = f2bu(wp[(size_t)co * CIN + c32 * 32 + kb * 8 + j]);
    *(short8*)(wpb + (size_t)u * 8) = *(short8*)o;
}

// ---------------- implicit-GEMM conv3d 3x3x3 via MFMA bf16 + reg-prefetch pipeline ----------------
// R6-proven mapping (4 cog x 2 sg, 80B pos stride); hoisted staging descriptors
// (goff int byte-offset, -1 = OOB; laddr -1 = idle) + DOUBLE REG BUFFER: chunk
// cc+1's 5 global loads issue BEFORE chunk cc's MFMA phase -> HBM/L2 latency
// hides under ~1000cy of MFMA. vmcnt wait lands after the next barrier.
template <int CIN_T>
__global__ __launch_bounds__(512, 2) void conv3d_mfma_k(const bf16* __restrict__ x,  // [b][p][CIN_T]
                                                        const bf16* __restrict__ wf, // [27][NC][128][4][8]
                                                        const float* __restrict__ bias,
                                                        bf16* __restrict__ y,        // [b][p][128]
                                                        float* __restrict__ gnacc) { // [64][2]
    constexpr int NC = CIN_T / 32;
    int blk = blockIdx.x;
    int hq = blk & 7;
    int d = (blk >> 3) & 31;
    int b = blk >> 8;
    int t = threadIdx.x;
    int lane = t & 63;
    int wid = t >> 6;
    int cog = wid >> 1;  // 0..3
    int sg = wid & 1;    // 0..1
    int lr = lane & 15;
    int kb = lane >> 4;

    __shared__ __align__(16) char xs[3 * 6 * 34 * 80];  // 48960 B
    __shared__ float gred[8][2];
    if (t < 16) gred[t >> 1][t & 1] = 0.f;

    // hoisted staging descriptors (invariant across cc)
    int goff[5];   // byte offset into x for chunk 0, or -1 if OOB/idle
    int laddr[5];  // LDS byte addr, or -1 if idle
#pragma unroll
    for (int i = 0; i < 5; ++i) {
        int e = t + i * 512;
        if (e < 612 * 4) {
            int ekb = e & 3;
            int pos = e >> 2;
            int ww = pos % 34;
            int hh = (pos / 34) % 6;
            int dd = pos / 204;
            int dz = d + dd - 1;
            int hz = hq * 4 + hh - 1;
            int wz = ww - 1;
            bool ok = (dz >= 0 && dz < RES && hz >= 0 && hz < RES && wz >= 0 && wz < RES);
            goff[i] = ok ? (int)((((size_t)b * R3 + dz * 1024 + hz * 32 + wz) * CIN_T + ekb * 8) * 2) : -1;
            laddr[i] = pos * 80 + ekb * 16;
        } else {
            goff[i] = -1;
            laddr[i] = -1;
        }
    }

    f32x4 acc[2][4];
#pragma unroll
    for (int r = 0; r < 2; ++r)
#pragma unroll
        for (int j = 0; j < 4; ++j) acc[r][j] = (f32x4){0.f, 0.f, 0.f, 0.f};

    int bbase[4];
#pragma unroll
    for (int j = 0; j < 4; ++j) {
        int sp = sg * 64 + j * 16 + lr;
        int hl = sp >> 5, wl = sp & 31;
        bbase[j] = (hl * 34 + wl) * 80 + kb * 16;
    }

    const char* xb = (const char*)x;
    const short8 zero8 = {0, 0, 0, 0, 0, 0, 0, 0};

    auto mfma_chunk = [&](int cc) {
        const short8* wfp = (const short8*)wf;
        size_t abase = ((size_t)cc * 128 + cog * 32 + lr) * 4 + kb;
#pragma unroll
        for (int dd = 0; dd < 3; ++dd)
#pragma unroll
            for (int dh = 0; dh < 3; ++dh)
#pragma unroll
                for (int dw = 0; dw < 3; ++dw) {
                    int tap = (dd * 3 + dh) * 3 + dw;
                    short8 a0 = wfp[abase + (size_t)tap * NC * 512];
                    short8 a1 = wfp[abase + (size_t)tap * NC * 512 + 64];
                    int toff = ((dd * 6 + dh) * 34 + dw) * 80;
                    short8 bb[4];
#pragma unroll
                    for (int j = 0; j < 4; ++j)
                        bb[j] = *(const short8*)(xs + bbase[j] + toff);
#pragma unroll
                    for (int j = 0; j < 4; ++j) {
                        acc[0][j] = __builtin_amdgcn_mfma_f32_16x16x32_bf16(a0, bb[j], acc[0][j], 0, 0, 0);
                        acc[1][j] = __builtin_amdgcn_mfma_f32_16x16x32_bf16(a1, bb[j], acc[1][j], 0, 0, 0);
                    }
                }
    };

    // prologue: load chunk 0 into regs (chunk stride = 32 elem * 2B = 64B)
    short8 va[5], vb2[5];
#pragma unroll
    for (int i = 0; i < 5; ++i) {
        va[i] = zero8;
        if (goff[i] >= 0) va[i] = *(const short8*)(xb + goff[i]);
    }

    for (int cc = 0; cc < NC; cc += 2) {
        // even chunk: write va, prefetch cc+1 into vb2
        __syncthreads();
#pragma unroll
        for (int i = 0; i < 5; ++i)
            if (laddr[i] >= 0) *(short8*)(xs + laddr[i]) = va[i];
#pragma unroll
        for (int i = 0; i < 5; ++i) {
            vb2[i] = zero8;
            if (goff[i] >= 0 && cc + 1 < NC) vb2[i] = *(const short8*)(xb + goff[i] + (cc + 1) * 64);
        }
        __syncthreads();
        mfma_chunk(cc);

        // odd chunk: write vb2, prefetch cc+2 into va
        __syncthreads();
#pragma unroll
        for (int i = 0; i < 5; ++i)
            if (laddr[i] >= 0) *(short8*)(xs + laddr[i]) = vb2[i];
#pragma unroll
        for (int i = 0; i < 5; ++i) {
            va[i] = zero8;
            if (goff[i] >= 0 && cc + 2 < NC) va[i] = *(const short8*)(xb + goff[i] + (cc + 2) * 64);
        }
        __syncthreads();
        mfma_chunk(cc + 1);
    }

    // epilogue: store bf16 + GN partial stats (group = cog*2 + r)
    float sred[2], ssred[2];
#pragma unroll
    for (int r = 0; r < 2; ++r) {
        int co = cog * 32 + r * 16 + kb * 4;
        float4 bv = *(const float4*)(bias + co);
        float s = 0.f, ss = 0.f;
#pragma unroll
        for (int j = 0; j < 4; ++j) {
            int sp = sg * 64 + j * 16 + lr;
            int p = d * 1024 + (hq * 4 + (sp >> 5)) * 32 + (sp & 31);
            float v0 = acc[r][j][0] + bv.x;
            float v1 = acc[r][j][1] + bv.y;
            float v2 = acc[r][j][2] + bv.z;
            float v3 = acc[r][j][3] + bv.w;
            ushort4 o;
            o.x = f2bu(v0); o.y = f2bu(v1); o.z = f2bu(v2); o.w = f2bu(v3);
            *(ushort4*)(y + ((size_t)b * R3 + p) * COUT + co) = o;
            s += v0 + v1 + v2 + v3;
            ss += v0 * v0 + v1 * v1 + v2 * v2 + v3 * v3;
        }
        sred[r] = s; ssred[r] = ss;
    }
#pragma unroll
    for (int m = 1; m < 64; m <<= 1) {
#pragma unroll
        for (int r = 0; r < 2; ++r) {
            sred[r] += __shfl_xor(sred[r], m, 64);
            ssred[r] += __shfl_xor(ssred[r], m, 64);
        }
    }
    if (lane == 0) {
#pragma unroll
        for (int r = 0; r < 2; ++r) {
            atomicAdd(&gred[cog * 2 + r][0], sred[r]);
            atomicAdd(&gred[cog * 2 + r][1], ssred[r]);
        }
    }
    __syncthreads();
    if (t < 16) atomicAdd(&gnacc[(b * 8 + (t >> 1)) * 2 + (t & 1)], gred[t >> 1][t & 1]);
}

// ---------------- GN apply + swish (act1, between convs) ----------------
__global__ __launch_bounds__(256) void gn_apply_cl_k(bf16* __restrict__ x,
                                                     const float* __restrict__ gnacc,
                                                     const float* __restrict__ gamma,
                                                     const float* __restrict__ beta) {
    int u = blockIdx.x * 256 + threadIdx.x;
    int ci8 = u & 15;
    int p = (u >> 4) & (R3 - 1);
    int b = u >> 19;
    int ci = ci8 * 8;
    int bg = b * 8 + (ci8 >> 1);
    const float M = (float)(GSIZE * R3);
    float s = gnacc[bg * 2], ss = gnacc[bg * 2 + 1];
    float mean = s / M;
    float istd = rsqrtf(fmaxf(ss / M - mean * mean, 0.f) + 1e-5f);
    bf16* ptr = x + ((size_t)b * R3 + p) * COUT + ci;
    short8 v = *(const short8*)ptr;
    ushort o[8];
#pragma unroll
    for (int j = 0; j < 8; ++j) {
        float f = b2f((ushort)v[j]);
        float yv = fmaf((f - mean) * istd, gamma[ci + j], beta[ci + j]);
        o[j] = f2bu(yv / (1.f + __expf(-yv)));
    }
    *(short8*)ptr = *(short8*)o;
}

// ---------------- point-branch GEMM via MFMA: pf bf16 + GN stats ----------------
__global__ __launch_bounds__(256) void pgemm_mfma_k(const bf16* __restrict__ featTb, // [g][64]
                                                    const bf16* __restrict__ wpb,    // [2][128][4][8]
                                                    const float* __restrict__ bp,
                                                    bf16* __restrict__ pfb,          // [g][128]
                                                    float* __restrict__ gnacc) {     // [64][2]
    int t = threadIdx.x;
    int lane = t & 63;
    int cog = t >> 6;       // 0..3
    int lr = lane & 15;
    int kb = lane >> 4;
    int g0 = blockIdx.x * 64;
    int b = g0 >> 14;

    __shared__ float gred[8][2];
    if (t < 16) gred[t >> 1][t & 1] = 0.f;
    __syncthreads();   // ensure gred init visible before any wave's atomicAdd

    f32x4 acc[2][4];
#pragma unroll
    for (int r = 0; r < 2; ++r)
#pragma unroll
        for (int j = 0; j < 4; ++j) acc[r][j] = (f32x4){0.f, 0.f, 0.f, 0.f};

    const short8* wfp = (const short8*)wpb;
    const short8* ftp = (const short8*)featTb;  // [g][8 octets]
#pragma unroll
    for (int cc = 0; cc < 2; ++cc) {
        size_t abase = ((size_t)cc * 128 + cog * 32 + lr) * 4 + kb;
        short8 a0 = wfp[abase];
        short8 a1 = wfp[abase + 64];
#pragma unroll
        for (int j = 0; j < 4; ++j) {
            short8 bb = ftp[(size_t)(g0 + j * 16 + lr) * 8 + cc * 4 + kb];
            acc[0][j] = __builtin_amdgcn_mfma_f32_16x16x32_bf16(a0, bb, acc[0][j], 0, 0, 0);
            acc[1][j] = __builtin_amdgcn_mfma_f32_16x16x32_bf16(a1, bb, acc[1][j], 0, 0, 0);
        }
    }

    float sred[2], ssred[2];
#pragma unroll
    for (int r = 0; r < 2; ++r) {
        int co = cog * 32 + r * 16 + kb * 4;
        float4 bv = *(const float4*)(bp + co);
        float s = 0.f, ss = 0.f;
#pragma unroll
        for (int j = 0; j < 4; ++j) {
            int g = g0 + j * 16 + lr;
            float v0 = acc[r][j][0] + bv.x;
            float v1 = acc[r][j][1] + bv.y;
            float v2 = acc[r][j][2] + bv.z;
            float v3 = acc[r][j][3] + bv.w;
            ushort4 o;
            o.x = f2bu(v0); o.y = f2bu(v1); o.z = f2bu(v2); o.w = f2bu(v3);
            *(ushort4*)(pfb + (size_t)g * COUT + co) = o;
            s += v0 + v1 + v2 + v3;
            ss += v0 * v0 + v1 * v1 + v2 * v2 + v3 * v3;
        }
        sred[r] = s; ssred[r] = ss;
    }
#pragma unroll
    for (int m = 1; m < 64; m <<= 1) {
#pragma unroll
        for (int r = 0; r < 2; ++r) {
            sred[r] += __shfl_xor(sred[r], m, 64);
            ssred[r] += __shfl_xor(ssred[r], m, 64);
        }
    }
    if (lane == 0) {
#pragma unroll
        for (int r = 0; r < 2; ++r) {
            atomicAdd(&gred[cog * 2 + r][0], sred[r]);
            atomicAdd(&gred[cog * 2 + r][1], ssred[r]);
        }
    }
    __syncthreads();
    if (t < 16) atomicAdd(&gnacc[(b * 8 + (t >> 1)) * 2 + (t & 1)], gred[t >> 1][t & 1]);
}

// ---------------- fuse2: 8 lanes/point; load pf + GN + swish + devox + add; bf16 IN PLACE ----------------
// Safe in place: pidx2 is a bijection over g; each (g, 16-ch slice) is read+written
// by exactly one thread; pgemm fully rewrites pfb each call (replay-deterministic).
__global__ __launch_bounds__(256) void fuse2_k(const bf16* __restrict__ vox,   // act2 [b][p][128]
                                               bf16* __restrict__ pfb,         // [g][128] in/out
                                               const float4* __restrict__ nc4,
                                               const unsigned int* __restrict__ pidx2,
                                               const float* __restrict__ gn2acc,
                                               const float* __restrict__ gnpacc,
                                               const float* __restrict__ g2g,
                                               const float* __restrict__ g2b,
                                               const float* __restrict__ gpg,
                                               const float* __restrict__ gpb) {
    int t = threadIdx.x;
    int u = blockIdx.x * 256 + t;
    int s = u >> 3;
    int l8 = u & 7;
    unsigned int g = pidx2[s];
    int b = (int)(g >> 14);
    int c0 = l8 * 16;

    const short8* pfp = (const short8*)(pfb + (size_t)g * COUT + c0);
    short8 p0 = pfp[0], p1 = pfp[1];
    float a[16];
#pragma unroll
    for (int j = 0; j < 8; ++j) { a[j] = b2f((ushort)p0[j]); a[8 + j] = b2f((ushort)p1[j]); }

    int bg = b * 8 + l8;
    const float M2 = (float)(GSIZE * R3);
    const float Mp = (float)(GSIZE * NPTS);
    float s2 = gn2acc[bg * 2], ss2 = gn2acc[bg * 2 + 1];
    float mean2 = s2 / M2;
    float istd2 = rsqrtf(fmaxf(ss2 / M2 - mean2 * mean2, 0.f) + 1e-5f);
    float sp = gnpacc[bg * 2], ssp = gnpacc[bg * 2 + 1];
    float meanp = sp / Mp;
    float istdp = rsqrtf(fmaxf(ssp / Mp - meanp * meanp, 0.f) + 1e-5f);
    float ga[16], gb[16];
#pragma unroll
    for (int j = 0; j < 16; ++j) {
        float gm = g2g[c0 + j];
        ga[j] = istd2 * gm;
        gb[j] = g2b[c0 + j] - mean2 * istd2 * gm;
    }

    float4 c4 = nc4[g];
    const float CMAX = (float)(RES - 1) - 1e-6f;
    float cx = fminf(c4.x, CMAX), cy = fminf(c4.y, CMAX), cz = fminf(c4.z, CMAX);
    int ix0 = (int)cx, iy0 = (int)cy, iz0 = (int)cz;
    float fx = cx - ix0, fy = cy - iy0, fz = cz - iz0;
    int ix1 = min(ix0 + 1, RES - 1), iy1 = min(iy0 + 1, RES - 1), iz1 = min(iz0 + 1, RES - 1);
    float gx0 = 1.f - fx, gy0 = 1.f - fy, gz0 = 1.f - fz;
    float wc[8] = {gx0 * gy0 * gz0, gx0 * gy0 * fz, gx0 * fy * gz0, gx0 * fy * fz,
                   fx * gy0 * gz0,  fx * gy0 * fz,  fx * fy * gz0,  fx * fy * fz};
    int fi[8];
    fi[0] = (ix0 * RES + iy0) * RES + iz0; fi[1] = (ix0 * RES + iy0) * RES + iz1;
    fi[2] = (ix0 * RES + iy1) * RES + iz0; fi[3] = (ix0 * RES + iy1) * RES + iz1;
    fi[4] = (ix1 * RES + iy0) * RES + iz0; fi[5] = (ix1 * RES + iy0) * RES + iz1;
    fi[6] = (ix1 * RES + iy1) * RES + iz0; fi[7] = (ix1 * RES + iy1) * RES + iz1;

    const bf16* vb = vox + (size_t)b * R3 * COUT + c0;
    float accv[16] = {0.f, 0.f, 0.f, 0.f, 0.f, 0.f, 0.f, 0.f,
                      0.f, 0.f, 0.f, 0.f, 0.f, 0.f, 0.f, 0.f};
#pragma unroll
    for (int f = 0; f < 8; ++f) {
        const short8* vp = (const short8*)(vb + (size_t)fi[f] * COUT);
        short8 v0 = vp[0], v1 = vp[1];
        float wgt = wc[f];
#pragma unroll
        for (int j = 0; j < 8; ++j) {
            float yv = fmaf(b2f((ushort)v0[j]), ga[j], gb[j]);
            accv[j] = fmaf(wgt, yv / (1.f + __expf(-yv)), accv[j]);
        }
#pragma unroll
        for (int j = 0; j < 8; ++j) {
            float yv = fmaf(b2f((ushort)v1[j]), ga[8 + j], gb[8 + j]);
            accv[8 + j] = fmaf(wgt, yv / (1.f + __expf(-yv)), accv[8 + j]);
        }
    }

    ushort outv[16];
#pragma unroll
    for (int j = 0; j < 16; ++j) {
        float pm = gpg[c0 + j];
        float yv = fmaf((a[j] - meanp) * istdp, pm, gpb[c0 + j]);
        outv[j] = f2bu(yv / (1.f + __expf(-yv)) + accv[j]);
    }
    bf16* pp = pfb + (size_t)g * COUT + c0;
    *(short8*)(pp) = *(short8*)(outv);
    *(short8*)(pp + 8) = *(short8*)(outv + 8);
}

// ---------------- transpose pfb bf16 [b][n][128] -> out fp32 [b][128][n] ----------------
__global__ __launch_bounds__(256) void transpose_out_k(const bf16* __restrict__ pfb,
                                                       float* __restrict__ out) {
    int blk = blockIdx.x;
    int b = blk >> 8, nt = blk & 255;
    int t = threadIdx.x;
    int n0 = nt * 64;
    __shared__ float lds[64][129];
#pragma unroll
    for (int k = 0; k < 4; ++k) {
        int e = t + k * 256;          // 1024 short8 loads: 64 rows x 16 octets (full 128 ch)
        int row = e >> 4, oct = e & 15;
        short8 v = *(const short8*)(pfb + (((size_t)b << 14) + n0 + row) * COUT + oct * 8);
#pragma unroll
        for (int j = 0; j < 8; ++j) lds[row][oct * 8 + j] = b2f((ushort)v[j]);
    }
    __syncthreads();
#pragma unroll
    for (int k = 0; k < 32; ++k) {
        int e = t + k * 256;
        int c = e >> 6, n = e & 63;
        out[((size_t)b * COUT + c) * NPTS + n0 + n] = lds[n][c];
    }
}

extern "C" void kernel_launch(void* const* d_in, const int* in_sizes, int n_in,
                              void* d_out, int out_size, void* d_ws, size_t ws_size,
                              hipStream_t stream) {
    const float* features = (const float*)d_in[0];
    const float* coords   = (const float*)d_in[1];
    const float* w1  = (const float*)d_in[3];
    const float* b1  = (const float*)d_in[4];
    const float* g1g = (const float*)d_in[5];
    const float* g1b = (const float*)d_in[6];
    const float* w2  = (const float*)d_in[7];
    const float* b2  = (const float*)d_in[8];
    const float* g2g = (const float*)d_in[9];
    const float* g2b = (const float*)d_in[10];
    const float* wp  = (const float*)d_in[11];
    const float* bp  = (const float*)d_in[12];
    const float* gpg = (const float*)d_in[13];
    const float* gpb = (const float*)d_in[14];
    float* out = (float*)d_out;

    // ws (~183 MB):
    //   [0,64MB)     act1 bf16 (dead after conv2)
    //   [64,128MB)   act2 bf16 (live until fuse2)
    //   [128,160MB)  voxCL bf16 -> pfb bf16 (overlay; voxCL dead after conv1)
    //   [160,176MB)  featTb bf16 (live until pgemm)
    //   tail: w1f, w2f, wpb, nc4, cnts, offs, vidx, slot, pidx2, part, stats
    char* ws = (char*)d_ws;
    size_t off = 0;
    bf16* act1 = (bf16*)(ws + off);          off += (size_t)BATCH * R3 * COUT * 2;  // 64MB
    bf16* act2 = (bf16*)(ws + off);          off += (size_t)BATCH * R3 * COUT * 2;  // 64MB
    bf16* voxCL = (bf16*)(ws + off);
    bf16* pfb = (bf16*)(ws + off);           off += (size_t)BATCH * R3 * CIN * 2;   // 32MB
    bf16* featTb = (bf16*)(ws + off);        off += (size_t)BATCH * NPTS * CIN * 2; // 16MB
    bf16* w1f = (bf16*)(ws + off);           off += (size_t)27 * 2 * 128 * 32 * 2;
    bf16* w2f = (bf16*)(ws + off);           off += (size_t)27 * 4 * 128 * 32 * 2;
    bf16* wpb = (bf16*)(ws + off);           off += (size_t)2 * 128 * 32 * 2;       // 16KB
    float4* nc4 = (float4*)(ws + off);       off += (size_t)BATCH * NPTS * 16;
    unsigned int* cnts = (unsigned int*)(ws + off);  off += (size_t)BATCH * R3 * 4;
    unsigned int* offs = (unsigned int*)(ws + off);  off += (size_t)BATCH * R3 * 4;
    int* vidx = (int*)(ws + off);            off += (size_t)BATCH * NPTS * 4;
    int* slot = (int*)(ws + off);            off += (size_t)BATCH * NPTS * 4;
    unsigned int* pidx2 = (unsigned int*)(ws + off); off += (size_t)BATCH * NPTS * 4;
    unsigned int* part = (unsigned int*)(ws + off);  off += 4096;
    float* bstats = (float*)(ws + off);      off += 256;
    float* gn1acc = (float*)(ws + off);      off += 512;
    float* gn2acc = (float*)(ws + off);      off += 512;
    float* gnpacc = (float*)(ws + off);      off += 512;

    hipMemsetAsync(cnts, 0, (size_t)BATCH * R3 * 4, stream);
    hipMemsetAsync(gn1acc, 0, 3 * 512, stream);

    coord_stats_k<<<BATCH, 256, 0, stream>>>(coords, bstats);
    vox_idx_k<<<BATCH * NPTS / 256, 256, 0, stream>>>(coords, bstats, nc4, vidx, slot, cnts);
    transpose_feats_k<<<BATCH * 256, 256, 0, stream>>>(features, featTb);
    scan1_k<<<BATCH * R3 / 256, 256, 0, stream>>>(cnts, offs, part);
    scan2_k<<<1, 1024, 0, stream>>>(part);
    scan3_k<<<BATCH * R3 / 256, 256, 0, stream>>>(offs, part);
    scatter_pts_k<<<BATCH * NPTS / 256, 256, 0, stream>>>(vidx, slot, offs, pidx2);
    gather_k<<<BATCH * R3 * 8 / 256, 256, 0, stream>>>(featTb, cnts, offs, pidx2, voxCL);

    wreorder_k<CIN><<<(27 * 2 * 128 * 4 + 255) / 256, 256, 0, stream>>>(w1, w1f);
    wreorder_k<COUT><<<(27 * 4 * 128 * 4 + 255) / 256, 256, 0, stream>>>(w2, w2f);
    wpreorder_k<<<4, 256, 0, stream>>>(wp, wpb);

    conv3d_mfma_k<CIN><<<BATCH * 32 * 8, 512, 0, stream>>>(voxCL, w1f, b1, act1, gn1acc);
    gn_apply_cl_k<<<BATCH * R3 * 16 / 256, 256, 0, stream>>>(act1, gn1acc, g1g, g1b);

    conv3d_mfma_k<COUT><<<BATCH * 32 * 8, 512, 0, stream>>>(act1, w2f, b2, act2, gn2acc);

    // pfb overlays voxCL (dead after conv1); launched after conv2 for safety
    pgemm_mfma_k<<<BATCH * NPTS / 64, 256, 0, stream>>>(featTb, wpb, bp, pfb, gnpacc);

    fuse2_k<<<BATCH * NPTS * 8 / 256, 256, 0, stream>>>(act2, pfb, nc4, pidx2,
                                                        gn2acc, gnpacc, g2g, g2b, gpg, gpb);

    transpose_out_k<<<BATCH * 256, 256, 0, stream>>>(pfb, out);
}

// Round 18
// 631.427 us; speedup vs baseline: 1.0984x; 1.0984x over previous
//
#include <hip/hip_runtime.h>
#include <hip/hip_bf16.h>
#include <cmath>

#define BATCH 8
#define CIN 64
#define COUT 128
#define NPTS 16384
#define RES 32
#define R3 32768
#define NGROUP 8
#define GSIZE 16

typedef __hip_bfloat16 bf16;
typedef __attribute__((ext_vector_type(8))) short short8;
typedef __attribute__((ext_vector_type(4))) float f32x4;

__device__ inline float b2f(ushort u) { union { float f; uint v; } x; x.v = ((uint)u) << 16; return x.f; }
__device__ inline ushort f2bu(float f) { __hip_bfloat16 h = __float2bfloat16(f); return *reinterpret_cast<ushort*>(&h); }

// ---------------- coord stats ----------------
__global__ __launch_bounds__(256) void coord_stats_k(const float* __restrict__ coords,
                                                     float* __restrict__ bstats) {
    int b = blockIdx.x;
    int t = threadIdx.x;
    __shared__ float red[256];
    __shared__ float means[3];
    for (int c = 0; c < 3; ++c) {
        float acc = 0.f;
        const float* p = coords + ((size_t)b * 3 + c) * NPTS;
        for (int n = t; n < NPTS; n += 256) acc += p[n];
        red[t] = acc; __syncthreads();
        for (int s = 128; s > 0; s >>= 1) { if (t < s) red[t] += red[t + s]; __syncthreads(); }
        if (t == 0) means[c] = red[0] * (1.f / NPTS);
        __syncthreads();
    }
    float m0 = means[0], m1 = means[1], m2 = means[2];
    const float* px = coords + ((size_t)b * 3 + 0) * NPTS;
    const float* py = coords + ((size_t)b * 3 + 1) * NPTS;
    const float* pz = coords + ((size_t)b * 3 + 2) * NPTS;
    float mx = 0.f;
    for (int n = t; n < NPTS; n += 256) {
        float dx = px[n] - m0, dy = py[n] - m1, dz = pz[n] - m2;
        mx = fmaxf(mx, sqrtf(dx * dx + dy * dy + dz * dz));
    }
    red[t] = mx; __syncthreads();
    for (int s = 128; s > 0; s >>= 1) { if (t < s) red[t] = fmaxf(red[t], red[t + s]); __syncthreads(); }
    if (t == 0) {
        bstats[b * 4 + 0] = m0; bstats[b * 4 + 1] = m1; bstats[b * 4 + 2] = m2;
        bstats[b * 4 + 3] = 1.f / (2.f * red[0]);
    }
}

// ---------------- per-point voxel index + nc4 + count ----------------
__global__ __launch_bounds__(256) void vox_idx_k(const float* __restrict__ coords,
                                                 const float* __restrict__ bstats,
                                                 float4* __restrict__ nc4,
                                                 int* __restrict__ vidx,
                                                 int* __restrict__ slot,
                                                 unsigned int* __restrict__ cnts) {
    int g = blockIdx.x * 256 + threadIdx.x;
    int b = g >> 14, n = g & (NPTS - 1);
    float m0 = bstats[b * 4 + 0], m1 = bstats[b * 4 + 1], m2 = bstats[b * 4 + 2];
    float sc = bstats[b * 4 + 3];
    float x = coords[((size_t)b * 3 + 0) * NPTS + n];
    float y = coords[((size_t)b * 3 + 1) * NPTS + n];
    float z = coords[((size_t)b * 3 + 2) * NPTS + n];
    float ncx = fminf(fmaxf(((x - m0) * sc + 0.5f) * (float)RES, 0.f), RES - 1.f);
    float ncy = fminf(fmaxf(((y - m1) * sc + 0.5f) * (float)RES, 0.f), RES - 1.f);
    float ncz = fminf(fmaxf(((z - m2) * sc + 0.5f) * (float)RES, 0.f), RES - 1.f);
    nc4[g] = make_float4(ncx, ncy, ncz, 0.f);
    int ix = min(max((int)rintf(ncx), 0), RES - 1);  // rintf = half-even = jnp.round
    int iy = min(max((int)rintf(ncy), 0), RES - 1);
    int iz = min(max((int)rintf(ncz), 0), RES - 1);
    int v = b * R3 + (ix * RES + iy) * RES + iz;
    vidx[g] = v;
    slot[g] = (int)atomicAdd(&cnts[v], 1u);
}

// ---------------- feature transpose: [b][64][N] fp32 -> [g][64] bf16 ----------------
__global__ __launch_bounds__(256) void transpose_feats_k(const float* __restrict__ feats,
                                                         bf16* __restrict__ featTb) {
    int blk = blockIdx.x;
    int b = blk >> 8, ntile = blk & 255;
    int t = threadIdx.x;
    __shared__ float lds[64][65];
    for (int e = t; e < 64 * 64; e += 256) {
        int c = e >> 6, n = e & 63;
        lds[c][n] = feats[((size_t)b * CIN + c) * NPTS + ntile * 64 + n];
    }
    __syncthreads();
    for (int e = t; e < 64 * 8; e += 256) {   // 512: (n, ci-octet)
        int n = e >> 3, oct = e & 7;
        ushort o[8];
#pragma unroll
        for (int j = 0; j < 8; ++j) o[j] = f2bu(lds[oct * 8 + j][n]);
        *(short8*)(featTb + ((((size_t)b << 14) + ntile * 64 + n) * CIN) + oct * 8) = *(short8*)o;
    }
}

// ---------------- scan ----------------
__global__ __launch_bounds__(256) void scan1_k(const unsigned int* __restrict__ cnts,
                                               unsigned int* __restrict__ offs,
                                               unsigned int* __restrict__ part) {
    int t = threadIdx.x;
    int g = blockIdx.x * 256 + t;
    unsigned int v = cnts[g];
    __shared__ unsigned int s[256];
    s[t] = v; __syncthreads();
    for (int d = 1; d < 256; d <<= 1) {
        unsigned int x = (t >= d) ? s[t - d] : 0u;
        __syncthreads();
        s[t] += x;
        __syncthreads();
    }
    offs[g] = s[t] - v;
    if (t == 255) part[blockIdx.x] = s[255];
}

__global__ __launch_bounds__(1024) void scan2_k(unsigned int* __restrict__ part) {
    int t = threadIdx.x;
    unsigned int v = part[t];
    __shared__ unsigned int s[1024];
    s[t] = v; __syncthreads();
    for (int d = 1; d < 1024; d <<= 1) {
        unsigned int x = (t >= d) ? s[t - d] : 0u;
        __syncthreads();
        s[t] += x;
        __syncthreads();
    }
    part[t] = s[t] - v;
}

__global__ __launch_bounds__(256) void scan3_k(unsigned int* __restrict__ offs,
                                               const unsigned int* __restrict__ part) {
    int g = blockIdx.x * 256 + threadIdx.x;
    offs[g] += part[blockIdx.x];
}

// ---------------- scatter global point id into CSR ----------------
__global__ __launch_bounds__(256) void scatter_pts_k(const int* __restrict__ vidx,
                                                     const int* __restrict__ slot,
                                                     const unsigned int* __restrict__ offs,
                                                     unsigned int* __restrict__ pidx2) {
    int g = blockIdx.x * 256 + threadIdx.x;
    int v = vidx[g];
    pidx2[offs[v] + slot[g]] = (unsigned int)g;
}

// ---------------- gather: CSR mean -> bf16 channel-last vox ----------------
__global__ __launch_bounds__(256) void gather_k(const bf16* __restrict__ featTb,
                                                const unsigned int* __restrict__ cnts,
                                                const unsigned int* __restrict__ offs,
                                                const unsigned int* __restrict__ pidx2,
                                                bf16* __restrict__ voxCL) {
    int u = blockIdx.x * 256 + threadIdx.x;
    int v = u >> 3;
    int l8 = u & 7;
    unsigned int cnt = cnts[v];
    unsigned int off = offs[v];
    float acc[8] = {0.f, 0.f, 0.f, 0.f, 0.f, 0.f, 0.f, 0.f};
    for (unsigned int i = 0; i < cnt; ++i) {
        unsigned int g = pidx2[off + i];
        short8 f = *(const short8*)(featTb + (size_t)g * CIN + l8 * 8);
#pragma unroll
        for (int j = 0; j < 8; ++j) acc[j] += b2f((ushort)f[j]);
    }
    float inv = 1.f / fmaxf((float)cnt, 1.f);
    ushort o[8];
#pragma unroll
    for (int j = 0; j < 8; ++j) o[j] = f2bu(acc[j] * inv);
    *(short8*)(voxCL + (size_t)v * CIN + l8 * 8) = *(short8*)o;
}

// ---------------- weight reorder: [co][ci][27] fp32 -> [t][c32][co][kb][8] bf16 ----------------
template <int CIN_T>
__global__ __launch_bounds__(256) void wreorder_k(const float* __restrict__ w,
                                                  bf16* __restrict__ wf) {
    const int NC = CIN_T / 32;
    int u = blockIdx.x * 256 + threadIdx.x;
    if (u >= 27 * NC * 128 * 4) return;
    int kb = u & 3;
    int co = (u >> 2) & 127;
    int c32 = (u >> 9) % NC;
    int t = u / (512 * NC);
    int cibase = c32 * 32 + kb * 8;
    ushort o[8];
#pragma unroll
    for (int j = 0; j < 8; ++j)
        o[j] = f2bu(w[((size_t)co * CIN_T + cibase + j) * 27 + t]);
    *(short8*)(wf + (size_t)u * 8) = *(short8*)o;
}

// ---------------- wp reorder: [co][64] fp32 -> [c32][co][kb][8] bf16 (MFMA A-frag order) ----------------
__global__ __launch_bounds__(256) void wpreorder_k(const float* __restrict__ wp,
                                                   bf16* __restrict__ wpb) {
    int u = blockIdx.x * 256 + threadIdx.x;  // 2*128*4 = 1024
    if (u >= 1024) return;
    int kb = u & 3;
    int co = (u >> 2) & 127;
    int c32 = u >> 9;
    ushort o[8];
#pragma unroll
    for (int j = 0; j < 8; ++j)
        o[j] = f2bu(wp[(size_t)co * CIN + c32 * 32 + kb * 8 + j]);
    *(short8*)(wpb + (size_t)u * 8) = *(short8*)o;
}

// ---------------- implicit-GEMM conv3d 3x3x3 via MFMA bf16 (R6/R16-proven, EXACT) ----------------
// block 512 = 8 waves (4 cog x 2 sg); 80B pos stride; 49KB LDS -> 3 blocks/CU.
// Measured: conv2 272us @ MfmaUtil 38% / occ 60% = ~853 TF effective (~95% of the
// 2-barrier structural ceiling). R9 d-pair: neutral. R17 reg-prefetch: -47us
// (occupancy loss > latency hidden). This structure is the plateau; do not touch.
template <int CIN_T>
__global__ __launch_bounds__(512, 2) void conv3d_mfma_k(const bf16* __restrict__ x,  // [b][p][CIN_T]
                                                        const bf16* __restrict__ wf, // [27][NC][128][4][8]
                                                        const float* __restrict__ bias,
                                                        bf16* __restrict__ y,        // [b][p][128]
                                                        float* __restrict__ gnacc) { // [64][2]
    constexpr int NC = CIN_T / 32;
    int blk = blockIdx.x;
    int hq = blk & 7;
    int d = (blk >> 3) & 31;
    int b = blk >> 8;
    int t = threadIdx.x;
    int lane = t & 63;
    int wid = t >> 6;
    int cog = wid >> 1;  // 0..3
    int sg = wid & 1;    // 0..1
    int lr = lane & 15;
    int kb = lane >> 4;

    __shared__ __align__(16) char xs[3 * 6 * 34 * 80];  // 48960 B
    __shared__ float gred[8][2];
    if (t < 16) gred[t >> 1][t & 1] = 0.f;

    f32x4 acc[2][4];
#pragma unroll
    for (int r = 0; r < 2; ++r)
#pragma unroll
        for (int j = 0; j < 4; ++j) acc[r][j] = (f32x4){0.f, 0.f, 0.f, 0.f};

    int bbase[4];
#pragma unroll
    for (int j = 0; j < 4; ++j) {
        int sp = sg * 64 + j * 16 + lr;
        int hl = sp >> 5, wl = sp & 31;
        bbase[j] = (hl * 34 + wl) * 80 + kb * 16;
    }

    for (int cc = 0; cc < NC; ++cc) {
        __syncthreads();
        for (int e = t; e < 612 * 4; e += 512) {
            int ekb = e & 3;
            int pos = e >> 2;
            int ww = pos % 34;
            int hh = (pos / 34) % 6;
            int dd = pos / 204;
            int dz = d + dd - 1;
            int hz = hq * 4 + hh - 1;
            int wz = ww - 1;
            short8 v = {0, 0, 0, 0, 0, 0, 0, 0};
            if (dz >= 0 && dz < RES && hz >= 0 && hz < RES && wz >= 0 && wz < RES)
                v = *(const short8*)(x + ((size_t)b * R3 + dz * 1024 + hz * 32 + wz) * CIN_T + cc * 32 + ekb * 8);
            *(short8*)(xs + pos * 80 + ekb * 16) = v;
        }
        __syncthreads();

        const short8* wfp = (const short8*)wf;
        size_t abase = ((size_t)cc * 128 + cog * 32 + lr) * 4 + kb;
#pragma unroll
        for (int dd = 0; dd < 3; ++dd)
#pragma unroll
            for (int dh = 0; dh < 3; ++dh)
#pragma unroll
                for (int dw = 0; dw < 3; ++dw) {
                    int tap = (dd * 3 + dh) * 3 + dw;
                    short8 a0 = wfp[abase + (size_t)tap * NC * 512];
                    short8 a1 = wfp[abase + (size_t)tap * NC * 512 + 64];
                    int toff = ((dd * 6 + dh) * 34 + dw) * 80;
                    short8 bb[4];
#pragma unroll
                    for (int j = 0; j < 4; ++j)
                        bb[j] = *(const short8*)(xs + bbase[j] + toff);
#pragma unroll
                    for (int j = 0; j < 4; ++j) {
                        acc[0][j] = __builtin_amdgcn_mfma_f32_16x16x32_bf16(a0, bb[j], acc[0][j], 0, 0, 0);
                        acc[1][j] = __builtin_amdgcn_mfma_f32_16x16x32_bf16(a1, bb[j], acc[1][j], 0, 0, 0);
                    }
                }
    }

    // epilogue: store bf16 + GN partial stats (group = cog*2 + r)
    float sred[2], ssred[2];
#pragma unroll
    for (int r = 0; r < 2; ++r) {
        int co = cog * 32 + r * 16 + kb * 4;
        float4 bv = *(const float4*)(bias + co);
        float s = 0.f, ss = 0.f;
#pragma unroll
        for (int j = 0; j < 4; ++j) {
            int sp = sg * 64 + j * 16 + lr;
            int p = d * 1024 + (hq * 4 + (sp >> 5)) * 32 + (sp & 31);
            float v0 = acc[r][j][0] + bv.x;
            float v1 = acc[r][j][1] + bv.y;
            float v2 = acc[r][j][2] + bv.z;
            float v3 = acc[r][j][3] + bv.w;
            ushort4 o;
            o.x = f2bu(v0); o.y = f2bu(v1); o.z = f2bu(v2); o.w = f2bu(v3);
            *(ushort4*)(y + ((size_t)b * R3 + p) * COUT + co) = o;
            s += v0 + v1 + v2 + v3;
            ss += v0 * v0 + v1 * v1 + v2 * v2 + v3 * v3;
        }
        sred[r] = s; ssred[r] = ss;
    }
#pragma unroll
    for (int m = 1; m < 64; m <<= 1) {
#pragma unroll
        for (int r = 0; r < 2; ++r) {
            sred[r] += __shfl_xor(sred[r], m, 64);
            ssred[r] += __shfl_xor(ssred[r], m, 64);
        }
    }
    if (lane == 0) {
#pragma unroll
        for (int r = 0; r < 2; ++r) {
            atomicAdd(&gred[cog * 2 + r][0], sred[r]);
            atomicAdd(&gred[cog * 2 + r][1], ssred[r]);
        }
    }
    __syncthreads();
    if (t < 16) atomicAdd(&gnacc[(b * 8 + (t >> 1)) * 2 + (t & 1)], gred[t >> 1][t & 1]);
}

// ---------------- GN apply + swish (act1, between convs) ----------------
__global__ __launch_bounds__(256) void gn_apply_cl_k(bf16* __restrict__ x,
                                                     const float* __restrict__ gnacc,
                                                     const float* __restrict__ gamma,
                                                     const float* __restrict__ beta) {
    int u = blockIdx.x * 256 + threadIdx.x;
    int ci8 = u & 15;
    int p = (u >> 4) & (R3 - 1);
    int b = u >> 19;
    int ci = ci8 * 8;
    int bg = b * 8 + (ci8 >> 1);
    const float M = (float)(GSIZE * R3);
    float s = gnacc[bg * 2], ss = gnacc[bg * 2 + 1];
    float mean = s / M;
    float istd = rsqrtf(fmaxf(ss / M - mean * mean, 0.f) + 1e-5f);
    bf16* ptr = x + ((size_t)b * R3 + p) * COUT + ci;
    short8 v = *(const short8*)ptr;
    ushort o[8];
#pragma unroll
    for (int j = 0; j < 8; ++j) {
        float f = b2f((ushort)v[j]);
        float yv = fmaf((f - mean) * istd, gamma[ci + j], beta[ci + j]);
        o[j] = f2bu(yv / (1.f + __expf(-yv)));
    }
    *(short8*)ptr = *(short8*)o;
}

// ---------------- point-branch GEMM via MFMA: pf bf16 + GN stats ----------------
__global__ __launch_bounds__(256) void pgemm_mfma_k(const bf16* __restrict__ featTb, // [g][64]
                                                    const bf16* __restrict__ wpb,    // [2][128][4][8]
                                                    const float* __restrict__ bp,
                                                    bf16* __restrict__ pfb,          // [g][128]
                                                    float* __restrict__ gnacc) {     // [64][2]
    int t = threadIdx.x;
    int lane = t & 63;
    int cog = t >> 6;       // 0..3
    int lr = lane & 15;
    int kb = lane >> 4;
    int g0 = blockIdx.x * 64;
    int b = g0 >> 14;

    __shared__ float gred[8][2];
    if (t < 16) gred[t >> 1][t & 1] = 0.f;
    __syncthreads();   // ensure gred init visible before any wave's atomicAdd

    f32x4 acc[2][4];
#pragma unroll
    for (int r = 0; r < 2; ++r)
#pragma unroll
        for (int j = 0; j < 4; ++j) acc[r][j] = (f32x4){0.f, 0.f, 0.f, 0.f};

    const short8* wfp = (const short8*)wpb;
    const short8* ftp = (const short8*)featTb;  // [g][8 octets]
#pragma unroll
    for (int cc = 0; cc < 2; ++cc) {
        size_t abase = ((size_t)cc * 128 + cog * 32 + lr) * 4 + kb;
        short8 a0 = wfp[abase];
        short8 a1 = wfp[abase + 64];
#pragma unroll
        for (int j = 0; j < 4; ++j) {
            short8 bb = ftp[(size_t)(g0 + j * 16 + lr) * 8 + cc * 4 + kb];
            acc[0][j] = __builtin_amdgcn_mfma_f32_16x16x32_bf16(a0, bb, acc[0][j], 0, 0, 0);
            acc[1][j] = __builtin_amdgcn_mfma_f32_16x16x32_bf16(a1, bb, acc[1][j], 0, 0, 0);
        }
    }

    float sred[2], ssred[2];
#pragma unroll
    for (int r = 0; r < 2; ++r) {
        int co = cog * 32 + r * 16 + kb * 4;
        float4 bv = *(const float4*)(bp + co);
        float s = 0.f, ss = 0.f;
#pragma unroll
        for (int j = 0; j < 4; ++j) {
            int g = g0 + j * 16 + lr;
            float v0 = acc[r][j][0] + bv.x;
            float v1 = acc[r][j][1] + bv.y;
            float v2 = acc[r][j][2] + bv.z;
            float v3 = acc[r][j][3] + bv.w;
            ushort4 o;
            o.x = f2bu(v0); o.y = f2bu(v1); o.z = f2bu(v2); o.w = f2bu(v3);
            *(ushort4*)(pfb + (size_t)g * COUT + co) = o;
            s += v0 + v1 + v2 + v3;
            ss += v0 * v0 + v1 * v1 + v2 * v2 + v3 * v3;
        }
        sred[r] = s; ssred[r] = ss;
    }
#pragma unroll
    for (int m = 1; m < 64; m <<= 1) {
#pragma unroll
        for (int r = 0; r < 2; ++r) {
            sred[r] += __shfl_xor(sred[r], m, 64);
            ssred[r] += __shfl_xor(ssred[r], m, 64);
        }
    }
    if (lane == 0) {
#pragma unroll
        for (int r = 0; r < 2; ++r) {
            atomicAdd(&gred[cog * 2 + r][0], sred[r]);
            atomicAdd(&gred[cog * 2 + r][1], ssred[r]);
        }
    }
    __syncthreads();
    if (t < 16) atomicAdd(&gnacc[(b * 8 + (t >> 1)) * 2 + (t & 1)], gred[t >> 1][t & 1]);
}

// ---------------- fuse2: 8 lanes/point; load pf + GN + swish + devox + add; bf16 IN PLACE ----------------
// Safe in place: pidx2 is a bijection over g; each (g, 16-ch slice) is read+written
// by exactly one thread; pgemm fully rewrites pfb each call (replay-deterministic).
__global__ __launch_bounds__(256) void fuse2_k(const bf16* __restrict__ vox,   // act2 [b][p][128]
                                               bf16* __restrict__ pfb,         // [g][128] in/out
                                               const float4* __restrict__ nc4,
                                               const unsigned int* __restrict__ pidx2,
                                               const float* __restrict__ gn2acc,
                                               const float* __restrict__ gnpacc,
                                               const float* __restrict__ g2g,
                                               const float* __restrict__ g2b,
                                               const float* __restrict__ gpg,
                                               const float* __restrict__ gpb) {
    int t = threadIdx.x;
    int u = blockIdx.x * 256 + t;
    int s = u >> 3;
    int l8 = u & 7;
    unsigned int g = pidx2[s];
    int b = (int)(g >> 14);
    int c0 = l8 * 16;

    const short8* pfp = (const short8*)(pfb + (size_t)g * COUT + c0);
    short8 p0 = pfp[0], p1 = pfp[1];
    float a[16];
#pragma unroll
    for (int j = 0; j < 8; ++j) { a[j] = b2f((ushort)p0[j]); a[8 + j] = b2f((ushort)p1[j]); }

    int bg = b * 8 + l8;
    const float M2 = (float)(GSIZE * R3);
    const float Mp = (float)(GSIZE * NPTS);
    float s2 = gn2acc[bg * 2], ss2 = gn2acc[bg * 2 + 1];
    float mean2 = s2 / M2;
    float istd2 = rsqrtf(fmaxf(ss2 / M2 - mean2 * mean2, 0.f) + 1e-5f);
    float sp = gnpacc[bg * 2], ssp = gnpacc[bg * 2 + 1];
    float meanp = sp / Mp;
    float istdp = rsqrtf(fmaxf(ssp / Mp - meanp * meanp, 0.f) + 1e-5f);
    float ga[16], gb[16];
#pragma unroll
    for (int j = 0; j < 16; ++j) {
        float gm = g2g[c0 + j];
        ga[j] = istd2 * gm;
        gb[j] = g2b[c0 + j] - mean2 * istd2 * gm;
    }

    float4 c4 = nc4[g];
    const float CMAX = (float)(RES - 1) - 1e-6f;
    float cx = fminf(c4.x, CMAX), cy = fminf(c4.y, CMAX), cz = fminf(c4.z, CMAX);
    int ix0 = (int)cx, iy0 = (int)cy, iz0 = (int)cz;
    float fx = cx - ix0, fy = cy - iy0, fz = cz - iz0;
    int ix1 = min(ix0 + 1, RES - 1), iy1 = min(iy0 + 1, RES - 1), iz1 = min(iz0 + 1, RES - 1);
    float gx0 = 1.f - fx, gy0 = 1.f - fy, gz0 = 1.f - fz;
    float wc[8] = {gx0 * gy0 * gz0, gx0 * gy0 * fz, gx0 * fy * gz0, gx0 * fy * fz,
                   fx * gy0 * gz0,  fx * gy0 * fz,  fx * fy * gz0,  fx * fy * fz};
    int fi[8];
    fi[0] = (ix0 * RES + iy0) * RES + iz0; fi[1] = (ix0 * RES + iy0) * RES + iz1;
    fi[2] = (ix0 * RES + iy1) * RES + iz0; fi[3] = (ix0 * RES + iy1) * RES + iz1;
    fi[4] = (ix1 * RES + iy0) * RES + iz0; fi[5] = (ix1 * RES + iy0) * RES + iz1;
    fi[6] = (ix1 * RES + iy1) * RES + iz0; fi[7] = (ix1 * RES + iy1) * RES + iz1;

    const bf16* vb = vox + (size_t)b * R3 * COUT + c0;
    float accv[16] = {0.f, 0.f, 0.f, 0.f, 0.f, 0.f, 0.f, 0.f,
                      0.f, 0.f, 0.f, 0.f, 0.f, 0.f, 0.f, 0.f};
#pragma unroll
    for (int f = 0; f < 8; ++f) {
        const short8* vp = (const short8*)(vb + (size_t)fi[f] * COUT);
        short8 v0 = vp[0], v1 = vp[1];
        float wgt = wc[f];
#pragma unroll
        for (int j = 0; j < 8; ++j) {
            float yv = fmaf(b2f((ushort)v0[j]), ga[j], gb[j]);
            accv[j] = fmaf(wgt, yv / (1.f + __expf(-yv)), accv[j]);
        }
#pragma unroll
        for (int j = 0; j < 8; ++j) {
            float yv = fmaf(b2f((ushort)v1[j]), ga[8 + j], gb[8 + j]);
            accv[8 + j] = fmaf(wgt, yv / (1.f + __expf(-yv)), accv[8 + j]);
        }
    }

    ushort outv[16];
#pragma unroll
    for (int j = 0; j < 16; ++j) {
        float pm = gpg[c0 + j];
        float yv = fmaf((a[j] - meanp) * istdp, pm, gpb[c0 + j]);
        outv[j] = f2bu(yv / (1.f + __expf(-yv)) + accv[j]);
    }
    bf16* pp = pfb + (size_t)g * COUT + c0;
    *(short8*)(pp) = *(short8*)(outv);
    *(short8*)(pp + 8) = *(short8*)(outv + 8);
}

// ---------------- transpose pfb bf16 [b][n][128] -> out fp32 [b][128][n] ----------------
__global__ __launch_bounds__(256) void transpose_out_k(const bf16* __restrict__ pfb,
                                                       float* __restrict__ out) {
    int blk = blockIdx.x;
    int b = blk >> 8, nt = blk & 255;
    int t = threadIdx.x;
    int n0 = nt * 64;
    __shared__ float lds[64][129];
#pragma unroll
    for (int k = 0; k < 4; ++k) {
        int e = t + k * 256;          // 1024 short8 loads: 64 rows x 16 octets (full 128 ch)
        int row = e >> 4, oct = e & 15;
        short8 v = *(const short8*)(pfb + (((size_t)b << 14) + n0 + row) * COUT + oct * 8);
#pragma unroll
        for (int j = 0; j < 8; ++j) lds[row][oct * 8 + j] = b2f((ushort)v[j]);
    }
    __syncthreads();
#pragma unroll
    for (int k = 0; k < 32; ++k) {
        int e = t + k * 256;
        int c = e >> 6, n = e & 63;
        out[((size_t)b * COUT + c) * NPTS + n0 + n] = lds[n][c];
    }
}

extern "C" void kernel_launch(void* const* d_in, const int* in_sizes, int n_in,
                              void* d_out, int out_size, void* d_ws, size_t ws_size,
                              hipStream_t stream) {
    const float* features = (const float*)d_in[0];
    const float* coords   = (const float*)d_in[1];
    const float* w1  = (const float*)d_in[3];
    const float* b1  = (const float*)d_in[4];
    const float* g1g = (const float*)d_in[5];
    const float* g1b = (const float*)d_in[6];
    const float* w2  = (const float*)d_in[7];
    const float* b2  = (const float*)d_in[8];
    const float* g2g = (const float*)d_in[9];
    const float* g2b = (const float*)d_in[10];
    const float* wp  = (const float*)d_in[11];
    const float* bp  = (const float*)d_in[12];
    const float* gpg = (const float*)d_in[13];
    const float* gpb = (const float*)d_in[14];
    float* out = (float*)d_out;

    // ws (~183 MB):
    //   [0,64MB)     act1 bf16 (dead after conv2)
    //   [64,128MB)   act2 bf16 (live until fuse2)
    //   [128,160MB)  voxCL bf16 -> pfb bf16 (overlay; voxCL dead after conv1)
    //   [160,176MB)  featTb bf16 (live until pgemm)
    //   tail: w1f, w2f, wpb, nc4, cnts, offs, vidx, slot, pidx2, part, stats
    char* ws = (char*)d_ws;
    size_t off = 0;
    bf16* act1 = (bf16*)(ws + off);          off += (size_t)BATCH * R3 * COUT * 2;  // 64MB
    bf16* act2 = (bf16*)(ws + off);          off += (size_t)BATCH * R3 * COUT * 2;  // 64MB
    bf16* voxCL = (bf16*)(ws + off);
    bf16* pfb = (bf16*)(ws + off);           off += (size_t)BATCH * R3 * CIN * 2;   // 32MB
    bf16* featTb = (bf16*)(ws + off);        off += (size_t)BATCH * NPTS * CIN * 2; // 16MB
    bf16* w1f = (bf16*)(ws + off);           off += (size_t)27 * 2 * 128 * 32 * 2;
    bf16* w2f = (bf16*)(ws + off);           off += (size_t)27 * 4 * 128 * 32 * 2;
    bf16* wpb = (bf16*)(ws + off);           off += (size_t)2 * 128 * 32 * 2;       // 16KB
    float4* nc4 = (float4*)(ws + off);       off += (size_t)BATCH * NPTS * 16;
    unsigned int* cnts = (unsigned int*)(ws + off);  off += (size_t)BATCH * R3 * 4;
    unsigned int* offs = (unsigned int*)(ws + off);  off += (size_t)BATCH * R3 * 4;
    int* vidx = (int*)(ws + off);            off += (size_t)BATCH * NPTS * 4;
    int* slot = (int*)(ws + off);            off += (size_t)BATCH * NPTS * 4;
    unsigned int* pidx2 = (unsigned int*)(ws + off); off += (size_t)BATCH * NPTS * 4;
    unsigned int* part = (unsigned int*)(ws + off);  off += 4096;
    float* bstats = (float*)(ws + off);      off += 256;
    float* gn1acc = (float*)(ws + off);      off += 512;
    float* gn2acc = (float*)(ws + off);      off += 512;
    float* gnpacc = (float*)(ws + off);      off += 512;

    hipMemsetAsync(cnts, 0, (size_t)BATCH * R3 * 4, stream);
    hipMemsetAsync(gn1acc, 0, 3 * 512, stream);

    coord_stats_k<<<BATCH, 256, 0, stream>>>(coords, bstats);
    vox_idx_k<<<BATCH * NPTS / 256, 256, 0, stream>>>(coords, bstats, nc4, vidx, slot, cnts);
    transpose_feats_k<<<BATCH * 256, 256, 0, stream>>>(features, featTb);
    scan1_k<<<BATCH * R3 / 256, 256, 0, stream>>>(cnts, offs, part);
    scan2_k<<<1, 1024, 0, stream>>>(part);
    scan3_k<<<BATCH * R3 / 256, 256, 0, stream>>>(offs, part);
    scatter_pts_k<<<BATCH * NPTS / 256, 256, 0, stream>>>(vidx, slot, offs, pidx2);
    gather_k<<<BATCH * R3 * 8 / 256, 256, 0, stream>>>(featTb, cnts, offs, pidx2, voxCL);

    wreorder_k<CIN><<<(27 * 2 * 128 * 4 + 255) / 256, 256, 0, stream>>>(w1, w1f);
    wreorder_k<COUT><<<(27 * 4 * 128 * 4 + 255) / 256, 256, 0, stream>>>(w2, w2f);
    wpreorder_k<<<4, 256, 0, stream>>>(wp, wpb);

    conv3d_mfma_k<CIN><<<BATCH * 32 * 8, 512, 0, stream>>>(voxCL, w1f, b1, act1, gn1acc);
    gn_apply_cl_k<<<BATCH * R3 * 16 / 256, 256, 0, stream>>>(act1, gn1acc, g1g, g1b);

    conv3d_mfma_k<COUT><<<BATCH * 32 * 8, 512, 0, stream>>>(act1, w2f, b2, act2, gn2acc);

    // pfb overlays voxCL (dead after conv1); launched after conv2 for safety
    pgemm_mfma_k<<<BATCH * NPTS / 64, 256, 0, stream>>>(featTb, wpb, bp, pfb, gnpacc);

    fuse2_k<<<BATCH * NPTS * 8 / 256, 256, 0, stream>>>(act2, pfb, nc4, pidx2,
                                                        gn2acc, gnpacc, g2g, g2b, gpg, gpb);

    transpose_out_k<<<BATCH * 256, 256, 0, stream>>>(pfb, out);
}